// Round 1
// baseline (3998.745 us; speedup 1.0000x reference)
//
#include <hip/hip_runtime.h>
#include <math.h>

#define N_NODES 50000
#define N_EDGES 200000
#define N_REL   4
#define FDIM    128
#define LDSROW  132   // 128 + 4 pad, keeps 16B alignment of rows

// ---------- degree / norm ----------
__global__ void deg_kernel(const int* __restrict__ dst, float* __restrict__ deg, int total) {
  int i = blockIdx.x * 256 + threadIdx.x;
  if (i < total) {
    int r = i / N_EDGES;
    atomicAdd(&deg[r * N_NODES + dst[i]], 1.0f);
  }
}

__global__ void norm_kernel(float* __restrict__ deg, int total) {
  int i = blockIdx.x * 256 + threadIdx.x;
  if (i < total) {
    float d = deg[i];
    deg[i] = d > 0.f ? 1.f / d : 0.f;
  }
}

// ---------- edge scatter: agg[dst] += hin[src] ----------
__global__ void scatter_kernel(const float* __restrict__ hin, const int* __restrict__ src,
                               const int* __restrict__ dst, float* __restrict__ agg) {
  int e  = blockIdx.x * 8 + (threadIdx.x >> 5);   // 8 edges/block, 32 lanes/edge
  int f4 = threadIdx.x & 31;
  int s = src[e], d = dst[e];
  float4 v = ((const float4*)(hin + (size_t)s * FDIM))[f4];
  float* a = agg + (size_t)d * FDIM + f4 * 4;
  atomicAdd(a + 0, v.x);
  atomicAdd(a + 1, v.y);
  atomicAdd(a + 2, v.z);
  atomicAdd(a + 3, v.w);
}

// ---------- conv GEMM: hout (+)= [relu](agg*norm @ W + b) ----------
__global__ void conv_kernel(const float* __restrict__ agg, const float* __restrict__ nrm,
                            const float* __restrict__ W, const float* __restrict__ bias,
                            float* __restrict__ hout, int accumulate, int do_relu) {
  __shared__ __align__(16) float et[64 * LDSROW];
  int tid  = threadIdx.x;
  int base = blockIdx.x * 64;

  // stage 64 scaled rows into LDS
  for (int j = 0; j < 8; ++j) {
    int flat = j * 256 + tid;
    int row  = flat >> 5;
    int f4   = flat & 31;
    int n    = base + row;
    float4 v = make_float4(0.f, 0.f, 0.f, 0.f);
    if (n < N_NODES) {
      v = ((const float4*)(agg + (size_t)n * FDIM))[f4];
      float s = nrm[n];
      v.x *= s; v.y *= s; v.z *= s; v.w *= s;
    }
    ((float4*)(et + row * LDSROW))[f4] = v;
  }
  __syncthreads();

  int cg = tid & 31;   // col group: cols 4cg..4cg+3
  int eg = tid >> 5;   // row group: rows eg*8..eg*8+7
  float acc[8][4];
#pragma unroll
  for (int e = 0; e < 8; ++e)
#pragma unroll
    for (int c = 0; c < 4; ++c) acc[e][c] = 0.f;

  const float* ebase = et + eg * 8 * LDSROW;
  for (int k = 0; k < FDIM; k += 4) {
    float4 w0 = ((const float4*)(W + (size_t)(k + 0) * FDIM))[cg];
    float4 w1 = ((const float4*)(W + (size_t)(k + 1) * FDIM))[cg];
    float4 w2 = ((const float4*)(W + (size_t)(k + 2) * FDIM))[cg];
    float4 w3 = ((const float4*)(W + (size_t)(k + 3) * FDIM))[cg];
#pragma unroll
    for (int e = 0; e < 8; ++e) {
      float4 ev = *(const float4*)(ebase + e * LDSROW + k);
      acc[e][0] += ev.x * w0.x + ev.y * w1.x + ev.z * w2.x + ev.w * w3.x;
      acc[e][1] += ev.x * w0.y + ev.y * w1.y + ev.z * w2.y + ev.w * w3.y;
      acc[e][2] += ev.x * w0.z + ev.y * w1.z + ev.z * w2.z + ev.w * w3.z;
      acc[e][3] += ev.x * w0.w + ev.y * w1.w + ev.z * w2.w + ev.w * w3.w;
    }
  }

  float4 bv = ((const float4*)bias)[cg];
#pragma unroll
  for (int e = 0; e < 8; ++e) {
    int n = base + eg * 8 + e;
    if (n < N_NODES) {
      float4 r;
      r.x = acc[e][0] + bv.x; r.y = acc[e][1] + bv.y;
      r.z = acc[e][2] + bv.z; r.w = acc[e][3] + bv.w;
      if (do_relu) {
        r.x = fmaxf(r.x, 0.f); r.y = fmaxf(r.y, 0.f);
        r.z = fmaxf(r.z, 0.f); r.w = fmaxf(r.w, 0.f);
      }
      float4* op = (float4*)(hout + (size_t)n * FDIM + 4 * cg);
      if (accumulate) {
        float4 o = *op;
        r.x += o.x; r.y += o.y; r.z += o.z; r.w += o.w;
      }
      *op = r;
    }
  }
}

// ---------- edge scoring: sigmoid over logit diff ----------
__global__ void edge_score_kernel(const float* __restrict__ h, const int* __restrict__ esrc,
                                  const int* __restrict__ edst,
                                  const float* __restrict__ P1w, const float* __restrict__ P1b,
                                  const float* __restrict__ P2w, const float* __restrict__ P2b,
                                  float* __restrict__ out) {
  __shared__ __align__(16) float et[64 * LDSROW];
  int tid  = threadIdx.x;
  int base = blockIdx.x * 64;

  // stage e = h[src]*h[dst] for 64 edges
  for (int j = 0; j < 8; ++j) {
    int flat = j * 256 + tid;
    int row  = flat >> 5;
    int f4   = flat & 31;
    int ge   = base + row;
    int s = esrc[ge], d = edst[ge];
    float4 a = ((const float4*)(h + (size_t)s * FDIM))[f4];
    float4 b = ((const float4*)(h + (size_t)d * FDIM))[f4];
    float4 p;
    p.x = a.x * b.x; p.y = a.y * b.y; p.z = a.z * b.z; p.w = a.w * b.w;
    ((float4*)(et + row * LDSROW))[f4] = p;
  }
  __syncthreads();

  int cg = tid & 31;
  int eg = tid >> 5;
  float acc[8][4];
#pragma unroll
  for (int e = 0; e < 8; ++e)
#pragma unroll
    for (int c = 0; c < 4; ++c) acc[e][c] = 0.f;

  const float* ebase = et + eg * 8 * LDSROW;
  for (int k = 0; k < FDIM; k += 4) {
    float4 w0 = ((const float4*)(P1w + (size_t)(k + 0) * FDIM))[cg];
    float4 w1 = ((const float4*)(P1w + (size_t)(k + 1) * FDIM))[cg];
    float4 w2 = ((const float4*)(P1w + (size_t)(k + 2) * FDIM))[cg];
    float4 w3 = ((const float4*)(P1w + (size_t)(k + 3) * FDIM))[cg];
#pragma unroll
    for (int e = 0; e < 8; ++e) {
      float4 ev = *(const float4*)(ebase + e * LDSROW + k);
      acc[e][0] += ev.x * w0.x + ev.y * w1.x + ev.z * w2.x + ev.w * w3.x;
      acc[e][1] += ev.x * w0.y + ev.y * w1.y + ev.z * w2.y + ev.w * w3.y;
      acc[e][2] += ev.x * w0.z + ev.y * w1.z + ev.z * w2.z + ev.w * w3.z;
      acc[e][3] += ev.x * w0.w + ev.y * w1.w + ev.z * w2.w + ev.w * w3.w;
    }
  }

  // z = relu(acc + P1b); logit_diff = z . (P2w[:,1]-P2w[:,0]) + (P2b[1]-P2b[0])
  int c0 = 4 * cg;
  float zb0 = P1b[c0 + 0], zb1 = P1b[c0 + 1], zb2 = P1b[c0 + 2], zb3 = P1b[c0 + 3];
  float wd0 = P2w[(c0 + 0) * 2 + 1] - P2w[(c0 + 0) * 2 + 0];
  float wd1 = P2w[(c0 + 1) * 2 + 1] - P2w[(c0 + 1) * 2 + 0];
  float wd2 = P2w[(c0 + 2) * 2 + 1] - P2w[(c0 + 2) * 2 + 0];
  float wd3 = P2w[(c0 + 3) * 2 + 1] - P2w[(c0 + 3) * 2 + 0];
  float cdiff = P2b[1] - P2b[0];

#pragma unroll
  for (int e = 0; e < 8; ++e) {
    float z0 = fmaxf(acc[e][0] + zb0, 0.f);
    float z1 = fmaxf(acc[e][1] + zb1, 0.f);
    float z2 = fmaxf(acc[e][2] + zb2, 0.f);
    float z3 = fmaxf(acc[e][3] + zb3, 0.f);
    float part = z0 * wd0 + z1 * wd1 + z2 * wd2 + z3 * wd3;
    // reduce over the 32 col-groups (lanes 0..31 / 32..63 stay disjoint)
    for (int off = 16; off > 0; off >>= 1) part += __shfl_xor(part, off);
    if (cg == 0) {
      float t = part + cdiff;
      out[base + eg * 8 + e] = 1.f / (1.f + expf(-t));
    }
  }
}

extern "C" void kernel_launch(void* const* d_in, const int* in_sizes, int n_in,
                              void* d_out, int out_size, void* d_ws, size_t ws_size,
                              hipStream_t stream) {
  const float* x   = (const float*)d_in[0];
  const float* W1  = (const float*)d_in[1];
  const float* b1  = (const float*)d_in[2];
  const float* W2  = (const float*)d_in[3];
  const float* b2  = (const float*)d_in[4];
  const float* P1w = (const float*)d_in[5];
  const float* P1b = (const float*)d_in[6];
  const float* P2w = (const float*)d_in[7];
  const float* P2b = (const float*)d_in[8];
  const int* src     = (const int*)d_in[9];
  const int* dst     = (const int*)d_in[10];
  const int* pos_src = (const int*)d_in[11];
  const int* pos_dst = (const int*)d_in[12];
  const int* neg_src = (const int*)d_in[13];
  const int* neg_dst = (const int*)d_in[14];
  float* out = (float*)d_out;

  float* ws   = (float*)d_ws;
  float* nrm  = ws;                                   // [4*N]
  float* agg  = nrm + (size_t)N_REL * N_NODES;        // [N*F]
  float* h1   = agg + (size_t)N_NODES * FDIM;         // [N*F]
  float* h2   = h1  + (size_t)N_NODES * FDIM;         // [N*F]

  // degrees -> norms (same graph for both layers)
  hipMemsetAsync(nrm, 0, (size_t)N_REL * N_NODES * sizeof(float), stream);
  deg_kernel<<<(N_REL * N_EDGES + 255) / 256, 256, 0, stream>>>(dst, nrm, N_REL * N_EDGES);
  norm_kernel<<<(N_REL * N_NODES + 255) / 256, 256, 0, stream>>>(nrm, N_REL * N_NODES);

  // layer 1: h1 = sum_r relu(conv_r(x))
  for (int r = 0; r < N_REL; ++r) {
    hipMemsetAsync(agg, 0, (size_t)N_NODES * FDIM * sizeof(float), stream);
    scatter_kernel<<<N_EDGES / 8, 256, 0, stream>>>(x, src + (size_t)r * N_EDGES,
                                                    dst + (size_t)r * N_EDGES, agg);
    conv_kernel<<<(N_NODES + 63) / 64, 256, 0, stream>>>(
        agg, nrm + (size_t)r * N_NODES, W1 + (size_t)r * FDIM * FDIM, b1 + (size_t)r * FDIM,
        h1, r > 0 ? 1 : 0, 1);
  }
  // layer 2: h2 = sum_r conv_r(h1), no relu
  for (int r = 0; r < N_REL; ++r) {
    hipMemsetAsync(agg, 0, (size_t)N_NODES * FDIM * sizeof(float), stream);
    scatter_kernel<<<N_EDGES / 8, 256, 0, stream>>>(h1, src + (size_t)r * N_EDGES,
                                                    dst + (size_t)r * N_EDGES, agg);
    conv_kernel<<<(N_NODES + 63) / 64, 256, 0, stream>>>(
        agg, nrm + (size_t)r * N_NODES, W2 + (size_t)r * FDIM * FDIM, b2 + (size_t)r * FDIM,
        h2, r > 0 ? 1 : 0, 0);
  }

  // edge scores: pos then neg (relation dim shares weights -> flat 800k edges each)
  edge_score_kernel<<<(N_REL * N_EDGES) / 64, 256, 0, stream>>>(
      h2, pos_src, pos_dst, P1w, P1b, P2w, P2b, out);
  edge_score_kernel<<<(N_REL * N_EDGES) / 64, 256, 0, stream>>>(
      h2, neg_src, neg_dst, P1w, P1b, P2w, P2b, out + (size_t)N_REL * N_EDGES);
}

// Round 2
// 1549.215 us; speedup vs baseline: 2.5811x; 2.5811x over previous
//
#include <hip/hip_runtime.h>
#include <math.h>

#define N_NODES 50000
#define N_EDGES 200000
#define N_REL   4
#define FDIM    128
#define LDSROW  132   // 128 + 4 pad, keeps 16B alignment of rows

// ---------- CSR build: counts ----------
__global__ void cnt_kernel(const int* __restrict__ dst, int* __restrict__ cnt) {
  int i = blockIdx.x * 256 + threadIdx.x;
  if (i < N_REL * N_EDGES) {
    int r = i / N_EDGES;
    atomicAdd(&cnt[r * N_NODES + dst[i]], 1);
  }
}

// ---------- norms from counts ----------
__global__ void norm_kernel(const int* __restrict__ cnt, float* __restrict__ nrm) {
  int i = blockIdx.x * 256 + threadIdx.x;
  if (i < N_REL * N_NODES) {
    int d = cnt[i];
    nrm[i] = d > 0 ? 1.f / (float)d : 0.f;
  }
}

// ---------- per-relation exclusive scan (one block of 1024 per relation) ----------
__global__ void scan_kernel(const int* __restrict__ cnt, int* __restrict__ row,
                            int* __restrict__ cursor) {
  int r = blockIdx.x;
  int t = threadIdx.x;                       // 1024 threads
  const int CH = (N_NODES + 1023) / 1024;    // 49
  int s = t * CH, e2 = min(s + CH, N_NODES);
  int sum = 0;
  for (int n = s; n < e2; ++n) { row[r * N_NODES + n] = sum; sum += cnt[r * N_NODES + n]; }
  __shared__ int ts[1024];
  ts[t] = sum;
  __syncthreads();
  for (int off = 1; off < 1024; off <<= 1) {
    int v = 0;
    if (t >= off) v = ts[t - off];
    __syncthreads();
    ts[t] += v;
    __syncthreads();
  }
  int prefix = (t > 0 ? ts[t - 1] : 0) + r * N_EDGES;
  for (int n = s; n < e2; ++n) {
    int v = row[r * N_NODES + n] + prefix;
    row[r * N_NODES + n] = v;
    cursor[r * N_NODES + n] = v;
  }
}

// ---------- CSR fill ----------
__global__ void fill_kernel(const int* __restrict__ src, const int* __restrict__ dst,
                            int* __restrict__ cursor, int* __restrict__ csr) {
  int i = blockIdx.x * 256 + threadIdx.x;
  if (i < N_REL * N_EDGES) {
    int r = i / N_EDGES;
    int pos = atomicAdd(&cursor[r * N_NODES + dst[i]], 1);
    csr[pos] = src[i];
  }
}

// ---------- fused gather + conv over all 4 relations ----------
// hout[n] = sum_r maybe_relu( (sum_{e in CSR_r(n)} hin[src_e]) * nrm_r[n] @ W_r + b_r )
__global__ void conv_fused_kernel(const float* __restrict__ hin, const int* __restrict__ row,
                                  const int* __restrict__ cnt, const float* __restrict__ nrm,
                                  const int* __restrict__ csr,
                                  const float* __restrict__ W, const float* __restrict__ bias,
                                  float* __restrict__ hout, int do_relu) {
  __shared__ __align__(16) float et[64 * LDSROW];
  int tid  = threadIdx.x;
  int base = blockIdx.x * 64;
  int cg = tid & 31;   // float4 column group
  int eg = tid >> 5;   // 32-lane group id (0..7)

  float tot[8][4];
#pragma unroll
  for (int e = 0; e < 8; ++e)
#pragma unroll
    for (int c = 0; c < 4; ++c) tot[e][c] = 0.f;

  for (int r = 0; r < N_REL; ++r) {
    if (r > 0) __syncthreads();   // protect et from previous GEMM readers

    // gather-stage 64 scaled rows: group eg handles rows eg, eg+8, ...
    for (int rr = eg; rr < 64; rr += 8) {
      int n = base + rr;
      float4 v = make_float4(0.f, 0.f, 0.f, 0.f);
      if (n < N_NODES) {
        int idx = r * N_NODES + n;
        int beg = row[idx], num = cnt[idx];
        for (int j = 0; j < num; ++j) {
          int s = csr[beg + j];
          float4 hv = ((const float4*)(hin + (size_t)s * FDIM))[cg];
          v.x += hv.x; v.y += hv.y; v.z += hv.z; v.w += hv.w;
        }
        float sc = nrm[idx];
        v.x *= sc; v.y *= sc; v.z *= sc; v.w *= sc;
      }
      ((float4*)(et + rr * LDSROW))[cg] = v;
    }
    __syncthreads();

    float acc[8][4];
#pragma unroll
    for (int e = 0; e < 8; ++e)
#pragma unroll
      for (int c = 0; c < 4; ++c) acc[e][c] = 0.f;

    const float* Wr    = W + (size_t)r * FDIM * FDIM;
    const float* ebase = et + eg * 8 * LDSROW;
    for (int k = 0; k < FDIM; k += 4) {
      float4 w0 = ((const float4*)(Wr + (size_t)(k + 0) * FDIM))[cg];
      float4 w1 = ((const float4*)(Wr + (size_t)(k + 1) * FDIM))[cg];
      float4 w2 = ((const float4*)(Wr + (size_t)(k + 2) * FDIM))[cg];
      float4 w3 = ((const float4*)(Wr + (size_t)(k + 3) * FDIM))[cg];
#pragma unroll
      for (int e = 0; e < 8; ++e) {
        float4 ev = *(const float4*)(ebase + e * LDSROW + k);
        acc[e][0] += ev.x * w0.x + ev.y * w1.x + ev.z * w2.x + ev.w * w3.x;
        acc[e][1] += ev.x * w0.y + ev.y * w1.y + ev.z * w2.y + ev.w * w3.y;
        acc[e][2] += ev.x * w0.z + ev.y * w1.z + ev.z * w2.z + ev.w * w3.z;
        acc[e][3] += ev.x * w0.w + ev.y * w1.w + ev.z * w2.w + ev.w * w3.w;
      }
    }

    float4 bv = ((const float4*)(bias + (size_t)r * FDIM))[cg];
#pragma unroll
    for (int e = 0; e < 8; ++e) {
      float v0 = acc[e][0] + bv.x, v1 = acc[e][1] + bv.y;
      float v2 = acc[e][2] + bv.z, v3 = acc[e][3] + bv.w;
      if (do_relu) {
        v0 = fmaxf(v0, 0.f); v1 = fmaxf(v1, 0.f);
        v2 = fmaxf(v2, 0.f); v3 = fmaxf(v3, 0.f);
      }
      tot[e][0] += v0; tot[e][1] += v1; tot[e][2] += v2; tot[e][3] += v3;
    }
  }

#pragma unroll
  for (int e = 0; e < 8; ++e) {
    int n = base + eg * 8 + e;
    if (n < N_NODES) {
      float4 o;
      o.x = tot[e][0]; o.y = tot[e][1]; o.z = tot[e][2]; o.w = tot[e][3];
      ((float4*)(hout + (size_t)n * FDIM))[cg] = o;
    }
  }
}

// ---------- edge scoring: sigmoid over logit diff ----------
__global__ void edge_score_kernel(const float* __restrict__ h, const int* __restrict__ esrc,
                                  const int* __restrict__ edst,
                                  const float* __restrict__ P1w, const float* __restrict__ P1b,
                                  const float* __restrict__ P2w, const float* __restrict__ P2b,
                                  float* __restrict__ out) {
  __shared__ __align__(16) float et[64 * LDSROW];
  int tid  = threadIdx.x;
  int base = blockIdx.x * 64;

  for (int j = 0; j < 8; ++j) {
    int flat = j * 256 + tid;
    int rown = flat >> 5;
    int f4   = flat & 31;
    int ge   = base + rown;
    int s = esrc[ge], d = edst[ge];
    float4 a = ((const float4*)(h + (size_t)s * FDIM))[f4];
    float4 b = ((const float4*)(h + (size_t)d * FDIM))[f4];
    float4 p;
    p.x = a.x * b.x; p.y = a.y * b.y; p.z = a.z * b.z; p.w = a.w * b.w;
    ((float4*)(et + rown * LDSROW))[f4] = p;
  }
  __syncthreads();

  int cg = tid & 31;
  int eg = tid >> 5;
  float acc[8][4];
#pragma unroll
  for (int e = 0; e < 8; ++e)
#pragma unroll
    for (int c = 0; c < 4; ++c) acc[e][c] = 0.f;

  const float* ebase = et + eg * 8 * LDSROW;
  for (int k = 0; k < FDIM; k += 4) {
    float4 w0 = ((const float4*)(P1w + (size_t)(k + 0) * FDIM))[cg];
    float4 w1 = ((const float4*)(P1w + (size_t)(k + 1) * FDIM))[cg];
    float4 w2 = ((const float4*)(P1w + (size_t)(k + 2) * FDIM))[cg];
    float4 w3 = ((const float4*)(P1w + (size_t)(k + 3) * FDIM))[cg];
#pragma unroll
    for (int e = 0; e < 8; ++e) {
      float4 ev = *(const float4*)(ebase + e * LDSROW + k);
      acc[e][0] += ev.x * w0.x + ev.y * w1.x + ev.z * w2.x + ev.w * w3.x;
      acc[e][1] += ev.x * w0.y + ev.y * w1.y + ev.z * w2.y + ev.w * w3.y;
      acc[e][2] += ev.x * w0.z + ev.y * w1.z + ev.z * w2.z + ev.w * w3.z;
      acc[e][3] += ev.x * w0.w + ev.y * w1.w + ev.z * w2.w + ev.w * w3.w;
    }
  }

  int c0 = 4 * cg;
  float zb0 = P1b[c0 + 0], zb1 = P1b[c0 + 1], zb2 = P1b[c0 + 2], zb3 = P1b[c0 + 3];
  float wd0 = P2w[(c0 + 0) * 2 + 1] - P2w[(c0 + 0) * 2 + 0];
  float wd1 = P2w[(c0 + 1) * 2 + 1] - P2w[(c0 + 1) * 2 + 0];
  float wd2 = P2w[(c0 + 2) * 2 + 1] - P2w[(c0 + 2) * 2 + 0];
  float wd3 = P2w[(c0 + 3) * 2 + 1] - P2w[(c0 + 3) * 2 + 0];
  float cdiff = P2b[1] - P2b[0];

#pragma unroll
  for (int e = 0; e < 8; ++e) {
    float z0 = fmaxf(acc[e][0] + zb0, 0.f);
    float z1 = fmaxf(acc[e][1] + zb1, 0.f);
    float z2 = fmaxf(acc[e][2] + zb2, 0.f);
    float z3 = fmaxf(acc[e][3] + zb3, 0.f);
    float part = z0 * wd0 + z1 * wd1 + z2 * wd2 + z3 * wd3;
    for (int off = 16; off > 0; off >>= 1) part += __shfl_xor(part, off);
    if (cg == 0) {
      float t = part + cdiff;
      out[base + eg * 8 + e] = 1.f / (1.f + expf(-t));
    }
  }
}

extern "C" void kernel_launch(void* const* d_in, const int* in_sizes, int n_in,
                              void* d_out, int out_size, void* d_ws, size_t ws_size,
                              hipStream_t stream) {
  const float* x   = (const float*)d_in[0];
  const float* W1  = (const float*)d_in[1];
  const float* b1  = (const float*)d_in[2];
  const float* W2  = (const float*)d_in[3];
  const float* b2  = (const float*)d_in[4];
  const float* P1w = (const float*)d_in[5];
  const float* P1b = (const float*)d_in[6];
  const float* P2w = (const float*)d_in[7];
  const float* P2b = (const float*)d_in[8];
  const int* src     = (const int*)d_in[9];
  const int* dst     = (const int*)d_in[10];
  const int* pos_src = (const int*)d_in[11];
  const int* pos_dst = (const int*)d_in[12];
  const int* neg_src = (const int*)d_in[13];
  const int* neg_dst = (const int*)d_in[14];
  float* out = (float*)d_out;

  char* ws = (char*)d_ws;
  int*   cnt    = (int*)ws;                                   ws += (size_t)N_REL * N_NODES * 4;
  int*   rowp   = (int*)ws;                                   ws += (size_t)N_REL * N_NODES * 4;
  int*   cursor = (int*)ws;                                   ws += (size_t)N_REL * N_NODES * 4;
  int*   csr    = (int*)ws;                                   ws += (size_t)N_REL * N_EDGES * 4;
  float* nrm    = (float*)ws;                                 ws += (size_t)N_REL * N_NODES * 4;
  float* h1     = (float*)ws;                                 ws += (size_t)N_NODES * FDIM * 4;
  float* h2     = (float*)ws;

  // ---- CSR build (shared by both layers) ----
  hipMemsetAsync(cnt, 0, (size_t)N_REL * N_NODES * 4, stream);
  cnt_kernel<<<(N_REL * N_EDGES + 255) / 256, 256, 0, stream>>>(dst, cnt);
  norm_kernel<<<(N_REL * N_NODES + 255) / 256, 256, 0, stream>>>(cnt, nrm);
  scan_kernel<<<N_REL, 1024, 0, stream>>>(cnt, rowp, cursor);
  fill_kernel<<<(N_REL * N_EDGES + 255) / 256, 256, 0, stream>>>(src, dst, cursor, csr);

  // ---- layer 1: h1 = sum_r relu(conv_r(x)) ----
  conv_fused_kernel<<<(N_NODES + 63) / 64, 256, 0, stream>>>(
      x, rowp, cnt, nrm, csr, W1, b1, h1, 1);
  // ---- layer 2: h2 = sum_r conv_r(h1) ----
  conv_fused_kernel<<<(N_NODES + 63) / 64, 256, 0, stream>>>(
      h1, rowp, cnt, nrm, csr, W2, b2, h2, 0);

  // ---- edge scores ----
  edge_score_kernel<<<(N_REL * N_EDGES) / 64, 256, 0, stream>>>(
      h2, pos_src, pos_dst, P1w, P1b, P2w, P2b, out);
  edge_score_kernel<<<(N_REL * N_EDGES) / 64, 256, 0, stream>>>(
      h2, neg_src, neg_dst, P1w, P1b, P2w, P2b, out + (size_t)N_REL * N_EDGES);
}

// Round 3
// 967.955 us; speedup vs baseline: 4.1311x; 1.6005x over previous
//
#include <hip/hip_runtime.h>
#include <math.h>

#define N_NODES 50000
#define N_EDGES 200000
#define N_REL   4
#define FDIM    128
#define LDSROW  132   // 128 + 4 pad for fp32 conv tiles

typedef __attribute__((ext_vector_type(8))) short short8;
typedef __attribute__((ext_vector_type(4))) float f32x4;

static __device__ __forceinline__ ushort f2bf(float f) {
  union { float f; unsigned u; } v; v.f = f;
  unsigned r = v.u + 0x7fff + ((v.u >> 16) & 1);   // RNE
  return (ushort)(r >> 16);
}

// ---------- CSR build: counts ----------
__global__ void cnt_kernel(const int* __restrict__ dst, int* __restrict__ cnt) {
  int i = blockIdx.x * 256 + threadIdx.x;
  if (i < N_REL * N_EDGES) {
    int r = i / N_EDGES;
    atomicAdd(&cnt[r * N_NODES + dst[i]], 1);
  }
}

__global__ void norm_kernel(const int* __restrict__ cnt, float* __restrict__ nrm) {
  int i = blockIdx.x * 256 + threadIdx.x;
  if (i < N_REL * N_NODES) {
    int d = cnt[i];
    nrm[i] = d > 0 ? 1.f / (float)d : 0.f;
  }
}

// ---------- per-relation exclusive scan ----------
__global__ void scan_kernel(const int* __restrict__ cnt, int* __restrict__ row,
                            int* __restrict__ cursor) {
  int r = blockIdx.x;
  int t = threadIdx.x;
  const int CH = (N_NODES + 1023) / 1024;
  int s = t * CH, e2 = min(s + CH, N_NODES);
  int sum = 0;
  for (int n = s; n < e2; ++n) { row[r * N_NODES + n] = sum; sum += cnt[r * N_NODES + n]; }
  __shared__ int ts[1024];
  ts[t] = sum;
  __syncthreads();
  for (int off = 1; off < 1024; off <<= 1) {
    int v = 0;
    if (t >= off) v = ts[t - off];
    __syncthreads();
    ts[t] += v;
    __syncthreads();
  }
  int prefix = (t > 0 ? ts[t - 1] : 0) + r * N_EDGES;
  for (int n = s; n < e2; ++n) {
    int v = row[r * N_NODES + n] + prefix;
    row[r * N_NODES + n] = v;
    cursor[r * N_NODES + n] = v;
  }
}

__global__ void fill_kernel(const int* __restrict__ src, const int* __restrict__ dst,
                            int* __restrict__ cursor, int* __restrict__ csr) {
  int i = blockIdx.x * 256 + threadIdx.x;
  if (i < N_REL * N_EDGES) {
    int r = i / N_EDGES;
    int pos = atomicAdd(&cursor[r * N_NODES + dst[i]], 1);
    csr[pos] = src[i];
  }
}

// ---------- fused gather + conv over all 4 relations (fp32) ----------
__global__ void conv_fused_kernel(const float* __restrict__ hin, const int* __restrict__ row,
                                  const int* __restrict__ cnt, const float* __restrict__ nrm,
                                  const int* __restrict__ csr,
                                  const float* __restrict__ W, const float* __restrict__ bias,
                                  float* __restrict__ hout, int do_relu) {
  __shared__ __align__(16) float et[64 * LDSROW];
  int tid  = threadIdx.x;
  int base = blockIdx.x * 64;
  int cg = tid & 31;
  int eg = tid >> 5;

  float tot[8][4];
#pragma unroll
  for (int e = 0; e < 8; ++e)
#pragma unroll
    for (int c = 0; c < 4; ++c) tot[e][c] = 0.f;

  for (int r = 0; r < N_REL; ++r) {
    if (r > 0) __syncthreads();

    for (int rr = eg; rr < 64; rr += 8) {
      int n = base + rr;
      float4 v = make_float4(0.f, 0.f, 0.f, 0.f);
      if (n < N_NODES) {
        int idx = r * N_NODES + n;
        int beg = row[idx], num = cnt[idx];
        for (int j = 0; j < num; ++j) {
          int s = csr[beg + j];
          float4 hv = ((const float4*)(hin + (size_t)s * FDIM))[cg];
          v.x += hv.x; v.y += hv.y; v.z += hv.z; v.w += hv.w;
        }
        float sc = nrm[idx];
        v.x *= sc; v.y *= sc; v.z *= sc; v.w *= sc;
      }
      ((float4*)(et + rr * LDSROW))[cg] = v;
    }
    __syncthreads();

    float acc[8][4];
#pragma unroll
    for (int e = 0; e < 8; ++e)
#pragma unroll
      for (int c = 0; c < 4; ++c) acc[e][c] = 0.f;

    const float* Wr    = W + (size_t)r * FDIM * FDIM;
    const float* ebase = et + eg * 8 * LDSROW;
    for (int k = 0; k < FDIM; k += 4) {
      float4 w0 = ((const float4*)(Wr + (size_t)(k + 0) * FDIM))[cg];
      float4 w1 = ((const float4*)(Wr + (size_t)(k + 1) * FDIM))[cg];
      float4 w2 = ((const float4*)(Wr + (size_t)(k + 2) * FDIM))[cg];
      float4 w3 = ((const float4*)(Wr + (size_t)(k + 3) * FDIM))[cg];
#pragma unroll
      for (int e = 0; e < 8; ++e) {
        float4 ev = *(const float4*)(ebase + e * LDSROW + k);
        acc[e][0] += ev.x * w0.x + ev.y * w1.x + ev.z * w2.x + ev.w * w3.x;
        acc[e][1] += ev.x * w0.y + ev.y * w1.y + ev.z * w2.y + ev.w * w3.y;
        acc[e][2] += ev.x * w0.z + ev.y * w1.z + ev.z * w2.z + ev.w * w3.z;
        acc[e][3] += ev.x * w0.w + ev.y * w1.w + ev.z * w2.w + ev.w * w3.w;
      }
    }

    float4 bv = ((const float4*)(bias + (size_t)r * FDIM))[cg];
#pragma unroll
    for (int e = 0; e < 8; ++e) {
      float v0 = acc[e][0] + bv.x, v1 = acc[e][1] + bv.y;
      float v2 = acc[e][2] + bv.z, v3 = acc[e][3] + bv.w;
      if (do_relu) {
        v0 = fmaxf(v0, 0.f); v1 = fmaxf(v1, 0.f);
        v2 = fmaxf(v2, 0.f); v3 = fmaxf(v3, 0.f);
      }
      tot[e][0] += v0; tot[e][1] += v1; tot[e][2] += v2; tot[e][3] += v3;
    }
  }

#pragma unroll
  for (int e = 0; e < 8; ++e) {
    int n = base + eg * 8 + e;
    if (n < N_NODES) {
      float4 o;
      o.x = tot[e][0]; o.y = tot[e][1]; o.z = tot[e][2]; o.w = tot[e][3];
      ((float4*)(hout + (size_t)n * FDIM))[cg] = o;
    }
  }
}

// ---------- prep: P1w^T in bf16 ----------
__global__ void prep_kernel(const float* __restrict__ P1w, ushort* __restrict__ bT) {
  int i = blockIdx.x * 256 + threadIdx.x;   // 16384 total
  int c = i >> 7, k = i & 127;
  bT[i] = f2bf(P1w[k * FDIM + c]);
}

// ---------- edge scoring via MFMA: one dispatch covers pos then neg ----------
__global__ __launch_bounds__(256) void edge_mfma_kernel(
    const float* __restrict__ h,
    const int* __restrict__ psrc, const int* __restrict__ pdst,
    const int* __restrict__ nsrc, const int* __restrict__ ndst,
    const ushort* __restrict__ bT, const float* __restrict__ P1b,
    const float* __restrict__ P2w, const float* __restrict__ P2b,
    float* __restrict__ out) {
  __shared__ __align__(16) short elds[64 * 128];   // bf16 E tile, XOR-swizzled
  __shared__ float partials[4][64];

  int tid  = threadIdx.x;
  int wave = tid >> 6, lane = tid & 63;
  int b = blockIdx.x;
  const int *esrc, *edst;
  float* o;
  int base;
  if (b < (N_REL * N_EDGES) / 64) {
    esrc = psrc; edst = pdst; o = out; base = b * 64;
  } else {
    esrc = nsrc; edst = ndst; o = out + (size_t)N_REL * N_EDGES;
    base = (b - (N_REL * N_EDGES) / 64) * 64;
  }

  // per-lane epilogue constants (cols 2*wave*16+(lane&15), +16)
  int c0 = (2 * wave) * 16 + (lane & 15);
  int c1 = c0 + 16;
  float bz0 = P1b[c0], bz1 = P1b[c1];
  float wd0 = P2w[c0 * 2 + 1] - P2w[c0 * 2];
  float wd1 = P2w[c1 * 2 + 1] - P2w[c1 * 2];
  float cdiff = P2b[1] - P2b[0];

  // B fragments in registers: bT[c][k] contiguous 8 bf16 along k
  short8 bfrag[2][4];
#pragma unroll
  for (int t2 = 0; t2 < 2; ++t2) {
    int c = (2 * wave + t2) * 16 + (lane & 15);
#pragma unroll
    for (int k0 = 0; k0 < 4; ++k0)
      bfrag[t2][k0] = *(const short8*)(bT + (size_t)c * 128 + k0 * 32 + (lane >> 4) * 8);
  }

  // stage E = bf16(h[src]*h[dst]) for 64 edges, swizzled
#pragma unroll
  for (int j = 0; j < 8; ++j) {
    int flat = j * 256 + tid;
    int row = flat >> 5, f4 = flat & 31;
    int ge = base + row;
    int s = esrc[ge], d = edst[ge];
    float4 a = ((const float4*)(h + (size_t)s * FDIM))[f4];
    float4 g = ((const float4*)(h + (size_t)d * FDIM))[f4];
    unsigned lo = (unsigned)f2bf(a.x * g.x) | ((unsigned)f2bf(a.y * g.y) << 16);
    unsigned hi = (unsigned)f2bf(a.z * g.z) | ((unsigned)f2bf(a.w * g.w) << 16);
    int byte = row * 256 + f4 * 8;
    byte ^= (row & 7) << 4;
    uint2* p = (uint2*)((char*)elds + byte);
    p->x = lo; p->y = hi;
  }
  __syncthreads();

  float part[4][4];
#pragma unroll
  for (int tr = 0; tr < 4; ++tr)
#pragma unroll
    for (int j2 = 0; j2 < 4; ++j2) part[tr][j2] = 0.f;

#pragma unroll
  for (int tr = 0; tr < 4; ++tr) {
    int arow = tr * 16 + (lane & 15);
    short8 afrag[4];
#pragma unroll
    for (int k0 = 0; k0 < 4; ++k0) {
      int byte = arow * 256 + k0 * 64 + (lane >> 4) * 16;
      byte ^= (arow & 7) << 4;
      afrag[k0] = *(const short8*)((const char*)elds + byte);
    }
#pragma unroll
    for (int t2 = 0; t2 < 2; ++t2) {
      f32x4 acc = {0.f, 0.f, 0.f, 0.f};
#pragma unroll
      for (int k0 = 0; k0 < 4; ++k0)
        acc = __builtin_amdgcn_mfma_f32_16x16x32_bf16(afrag[k0], bfrag[t2][k0], acc, 0, 0, 0);
      float bz = t2 ? bz1 : bz0;
      float wdv = t2 ? wd1 : wd0;
#pragma unroll
      for (int j2 = 0; j2 < 4; ++j2)
        part[tr][j2] += fmaxf(acc[j2] + bz, 0.f) * wdv;
    }
  }

  // reduce across the 16 col-lanes in each group; lane&15==0 holds rows (lane>>4)*4+j2
#pragma unroll
  for (int tr = 0; tr < 4; ++tr)
#pragma unroll
    for (int j2 = 0; j2 < 4; ++j2) {
      float v = part[tr][j2];
      v += __shfl_xor(v, 1);
      v += __shfl_xor(v, 2);
      v += __shfl_xor(v, 4);
      v += __shfl_xor(v, 8);
      if ((lane & 15) == 0) partials[wave][tr * 16 + (lane >> 4) * 4 + j2] = v;
    }
  __syncthreads();

  if (tid < 64) {
    float s2 = partials[0][tid] + partials[1][tid] + partials[2][tid] + partials[3][tid] + cdiff;
    o[base + tid] = 1.f / (1.f + expf(-s2));
  }
}

extern "C" void kernel_launch(void* const* d_in, const int* in_sizes, int n_in,
                              void* d_out, int out_size, void* d_ws, size_t ws_size,
                              hipStream_t stream) {
  const float* x   = (const float*)d_in[0];
  const float* W1  = (const float*)d_in[1];
  const float* b1  = (const float*)d_in[2];
  const float* W2  = (const float*)d_in[3];
  const float* b2  = (const float*)d_in[4];
  const float* P1w = (const float*)d_in[5];
  const float* P1b = (const float*)d_in[6];
  const float* P2w = (const float*)d_in[7];
  const float* P2b = (const float*)d_in[8];
  const int* src     = (const int*)d_in[9];
  const int* dst     = (const int*)d_in[10];
  const int* pos_src = (const int*)d_in[11];
  const int* pos_dst = (const int*)d_in[12];
  const int* neg_src = (const int*)d_in[13];
  const int* neg_dst = (const int*)d_in[14];
  float* out = (float*)d_out;

  char* ws = (char*)d_ws;
  int*    cnt    = (int*)ws;     ws += (size_t)N_REL * N_NODES * 4;
  int*    rowp   = (int*)ws;     ws += (size_t)N_REL * N_NODES * 4;
  int*    cursor = (int*)ws;     ws += (size_t)N_REL * N_NODES * 4;
  int*    csr    = (int*)ws;     ws += (size_t)N_REL * N_EDGES * 4;
  float*  nrm    = (float*)ws;   ws += (size_t)N_REL * N_NODES * 4;
  ushort* bT     = (ushort*)ws;  ws += (size_t)FDIM * FDIM * 2;
  float*  h1     = (float*)ws;   ws += (size_t)N_NODES * FDIM * 4;
  float*  h2     = (float*)ws;

  // ---- CSR build (shared by both layers) + weight prep ----
  hipMemsetAsync(cnt, 0, (size_t)N_REL * N_NODES * 4, stream);
  cnt_kernel<<<(N_REL * N_EDGES + 255) / 256, 256, 0, stream>>>(dst, cnt);
  norm_kernel<<<(N_REL * N_NODES + 255) / 256, 256, 0, stream>>>(cnt, nrm);
  scan_kernel<<<N_REL, 1024, 0, stream>>>(cnt, rowp, cursor);
  fill_kernel<<<(N_REL * N_EDGES + 255) / 256, 256, 0, stream>>>(src, dst, cursor, csr);
  prep_kernel<<<(FDIM * FDIM) / 256, 256, 0, stream>>>(P1w, bT);

  // ---- layer 1 / layer 2 ----
  conv_fused_kernel<<<(N_NODES + 63) / 64, 256, 0, stream>>>(
      x, rowp, cnt, nrm, csr, W1, b1, h1, 1);
  conv_fused_kernel<<<(N_NODES + 63) / 64, 256, 0, stream>>>(
      h1, rowp, cnt, nrm, csr, W2, b2, h2, 0);

  // ---- edge scores: pos blocks then neg blocks in one dispatch ----
  edge_mfma_kernel<<<2 * (N_REL * N_EDGES) / 64, 256, 0, stream>>>(
      h2, pos_src, pos_dst, neg_src, neg_dst, bT, P1b, P2w, P2b, out);
}